// Round 4
// baseline (116.337 us; speedup 1.0000x reference)
//
#include <hip/hip_runtime.h>
#include <math.h>

// Biquad highpass IIR over [B=128, C=2, T=65536] f32.
// R8: R7's proven per-group pipeline (traffic shapes byte-identical), with
// TWO consecutive 32-chunk groups fused per block (grid 2048 = 8 waves/CU,
// single generation). Group 0's terminal 16-instr store burst now sits in
// the vmcnt queue AHEAD of group 1's prologue loads: the same WAITVM(8)
// that waits for group 1's t0 also retires group 0's stores, so stores and
// next-group loads are in flight simultaneously from the same wave (mixed
// HBM stream per wave instead of phase-separated bursts + per-wave drain).
// Empirical rules carried from R4-R7 counter evidence:
//   READS:  per-instr segments >=128B contiguous (here 256B @ 512B stride);
//           warm re-reads are intra-block L2 hits => FETCH ~1x compulsory.
//   WRITES: 16 instrs x 1KB contiguous, terminal per group, covering an
//           aligned 16KB region/wave (proven 1x; R5's 256B pieces => 2x,
//           R6's shape => 6.6x).
//   OCCUPANCY: >=8 waves/CU suffices (traffic-limited, not latency-limited).
// Numerics: W=64 zero-state warm-up (pole radius 0.8234 => boundary error
// ~4e-6); absmax floor 0.0156 = f32 contraction noise, proven R1-R7.

#define T_LEN    65536
#define L_CHUNK  128
#define W_WARM   64
#define TS       64
#define BLK      64                  // one wave per block
#define ROWS     32                  // chunks per group
#define GROUPS   2                   // groups per block
#define BUF_F    (ROWS * TS)         // 2048 floats = 8 KiB per buffer
#define BLOCKS_PER_CH ((T_LEN / L_CHUNK) / (ROWS * GROUPS))   // 8

#define WAITVM(n) asm volatile("s_waitcnt vmcnt(" #n ")" ::: "memory")

__device__ __forceinline__ void lds_fence() {
    // orders DS ops (in-order per wave; block = one wave) without draining vmcnt
    asm volatile("s_waitcnt lgkmcnt(0)" ::: "memory");
}

// DMA one 8 KiB tile (32 rows x 64 floats) into LDS; 8 instructions of
// 64 lanes x 16B. Instr i covers rows i*4..i*4+3: per instr 4 x 256B
// contiguous segments at 512B stride (full-line reads, proven clean).
// LDS layout: slot s = r*16 + m holds row r's logical float4
// j = (m - (r&7)) & 15  (rotation spreads compute/store reads over banks).
// Lane mapping: r = i*4 + (lane>>4), m = lane&15 => per-lane global source
// offset depends only on lane and i-parity (two hoisted bases).
__device__ __forceinline__ void dma_tile(const float* __restrict__ x,
                                         int bE, int bO, int tile, float* buf)
{
    #pragma unroll
    for (int i = 0; i < 8; ++i) {
        int pos = ((i & 1) ? bO : bE) + i * 512 + tile * TS;  // 4 rows*128 = 512
        pos = pos < 0 ? 0 : pos;     // global row 0 pre-signal clamp (zeroed later)
        __builtin_amdgcn_global_load_lds(
            (__attribute__((address_space(1))) void*)(void*)(x + pos),
            (__attribute__((address_space(3))) void*)(buf + i * 256),
            16, 0, 0);
    }
}

// Process one 64-sample tile for this lane's chunk (lanes 0..31 only).
template <bool WARM>
__device__ __forceinline__ void tile_filter(float* buf, int l, bool zr,
    float c_b0, float c_b1, float c_b2, float c_a1, float c_a2,
    float& x1, float& x2, float& y1, float& y2)
{
    float4 r[16];
    #pragma unroll
    for (int j = 0; j < 16; ++j)
        r[j] = *(float4*)&buf[(l * 16 + ((j + (l & 7)) & 15)) * 4];

    if (WARM && zr) {   // channel-start row: pre-channel reads are garbage => state 0
        #pragma unroll
        for (int j = 0; j < 16; ++j) r[j] = make_float4(0.f, 0.f, 0.f, 0.f);
    }

    #pragma unroll
    for (int j = 0; j < 16; ++j) {
        float4 v = r[j];
        float yv;
        yv = c_b0*v.x + c_b1*x1 + c_b2*x2 - c_a1*y1 - c_a2*y2;
        x2 = x1; x1 = v.x; y2 = y1; y1 = yv; v.x = yv;
        yv = c_b0*v.y + c_b1*x1 + c_b2*x2 - c_a1*y1 - c_a2*y2;
        x2 = x1; x1 = v.y; y2 = y1; y1 = yv; v.y = yv;
        yv = c_b0*v.z + c_b1*x1 + c_b2*x2 - c_a1*y1 - c_a2*y2;
        x2 = x1; x1 = v.z; y2 = y1; y1 = yv; v.z = yv;
        yv = c_b0*v.w + c_b1*x1 + c_b2*x2 - c_a1*y1 - c_a2*y2;
        x2 = x1; x1 = v.w; y2 = y1; y1 = yv; v.w = yv;
        if (!WARM) r[j] = v;
    }

    if (!WARM) {         // in-place: staging buffer becomes output buffer
        #pragma unroll
        for (int j = 0; j < 16; ++j)
            *(float4*)&buf[(l * 16 + ((j + (l & 7)) & 15)) * 4] = r[j];
    }
}

// One 32-chunk group: R7's full pipeline. Issues its 16 terminal stores and
// returns WITHOUT waiting on them -- the caller's next group's WAITVM(8)
// (queue: [stores(16), t0(8), t1(8)], wait<=8) retires them for free while
// its own loads are in flight.
__device__ __forceinline__ void process_group(
    const float* __restrict__ x, float* __restrict__ y,
    int lane, int cg0, bool zr,
    float* bufA, float* bufB,
    float c_b0, float c_b1, float c_b2, float c_a1, float c_a2)
{
    // per-lane DMA source bases: row-quarter rq = lane>>4, permuted float4 j
    // (rotation rot = r&7 = (i&1)*4 + rq  => two bases, even/odd instr)
    const int rq = lane >> 4;
    const int m  = lane & 15;
    const int jE = (m - rq) & 15;
    const int jO = (m - rq - 4) & 15;
    const int rowbase = (cg0 + rq) * L_CHUNK - W_WARM;
    const int bE = rowbase + jE * 4;
    const int bO = rowbase + jO * 4;

    float x1 = 0.f, x2 = 0.f, y1 = 0.f, y2 = 0.f;

    // ---- 3-tile pipeline (t0 warm, t1/t2 live), 2 buffers, counted vmcnt ----
    dma_tile(x, bE, bO, 0, bufA);              // +8
    dma_tile(x, bE, bO, 1, bufB);              // +8

    WAITVM(8);                                  // t0 landed (and prev group's stores retired)
    if (lane < ROWS)
        tile_filter<true>(bufA, lane, zr, c_b0, c_b1, c_b2, c_a1, c_a2, x1, x2, y1, y2);
    lds_fence();                                // A's reads retired before refill
    dma_tile(x, bE, bO, 2, bufA);              // +8

    WAITVM(8);                                  // t1 landed (t2 still in flight)
    if (lane < ROWS)
        tile_filter<false>(bufB, lane, false, c_b0, c_b1, c_b2, c_a1, c_a2, x1, x2, y1, y2);

    WAITVM(0);                                  // t2 landed
    if (lane < ROWS)
        tile_filter<false>(bufA, lane, false, c_b0, c_b1, c_b2, c_a1, c_a2, x1, x2, y1, y2);
    lds_fence();                                // in-place writes ordered before store reads

    // ---- R4-shape store: 16 instructions x 1 KiB contiguous, covering the
    // group's aligned 16 KiB y-region whole (proven 1x writes). y float4
    // q = k*64+lane: chunk c=q>>5, w=q&31; w<16 -> bufB (samples 0-63),
    // else bufA (64-127); slot = c*16 + (((w&15) + (c&7)) & 15). ----
    const int yb4 = cg0 * (L_CHUNK / 4);        // float4 index base = cg0*32
    #pragma unroll
    for (int k = 0; k < 16; ++k) {
        int q  = k * 64 + lane;
        int c  = q >> 5;
        int w  = q & 31;
        float* b = (w < 16) ? bufB : bufA;
        int mm = ((w & 15) + (c & 7)) & 15;
        float4 v = *(float4*)&b[(c * 16 + mm) * 4];
        *(float4*)(y + 4 * (yb4 + q)) = v;
    }
    // no store wait: next group's WAITVM(8) covers retirement
}

__global__ __launch_bounds__(BLK, 4)
void hp_biquad_kernel(const float* __restrict__ x, float* __restrict__ y,
                      float c_b0, float c_b1, float c_b2, float c_a1, float c_a2)
{
    __shared__ float bufA[BUF_F];
    __shared__ float bufB[BUF_F];
    const int lane = threadIdx.x;

    // block covers groups 2b, 2b+1 (chunks 64b .. 64b+63). Channel = 512
    // chunks = 16 groups = 8 blocks; only group 0 of a channel-first block
    // starts a channel (group 2b+1 has odd index, never == 0 mod 16).
    const int g0   = blockIdx.x * GROUPS;
    const bool chf = (blockIdx.x & (BLOCKS_PER_CH - 1)) == 0;

    process_group(x, y, lane, g0 * ROWS, chf && (lane == 0),
                  bufA, bufB, c_b0, c_b1, c_b2, c_a1, c_a2);
    lds_fence();   // store-loop ds_reads retired before group-1 DMA refill
    process_group(x, y, lane, (g0 + 1) * ROWS, false,
                  bufA, bufB, c_b0, c_b1, c_b2, c_a1, c_a2);
}

extern "C" void kernel_launch(void* const* d_in, const int* in_sizes, int n_in,
                              void* d_out, int out_size, void* d_ws, size_t ws_size,
                              hipStream_t stream)
{
    const float* x = (const float*)d_in[0];
    float* y = (float*)d_out;

    // Same double-precision coefficient math as the reference, cast to f32.
    const double SR = 16000.0, FLO = 200.0, FHI = 1200.0;
    const double freq   = 0.5 * (FLO + FHI);      // 700 Hz
    const double cutoff = freq / SR;
    const double q      = 0.70710678;
    const double w0 = 2.0 * M_PI * cutoff;
    const double cw = cos(w0), sw = sin(w0);
    const double alpha = sw / (2.0 * q);
    const double b0 = (1.0 + cw) / 2.0;
    const double b1 = -(1.0 + cw);
    const double b2 = (1.0 + cw) / 2.0;
    const double a0 = 1.0 + alpha;
    const double a1 = -2.0 * cw;
    const double a2 = 1.0 - alpha;
    const float fb0 = (float)(b0 / a0), fb1 = (float)(b1 / a0), fb2 = (float)(b2 / a0);
    const float fa1 = (float)(a1 / a0), fa2 = (float)(a2 / a0);

    const int total  = 128 * 2 * T_LEN;            // 16,777,216 samples
    const int chunks = total / L_CHUNK;            // 131,072
    const int blocks = chunks / (ROWS * GROUPS);   // 2048 single-wave blocks

    hp_biquad_kernel<<<blocks, BLK, 0, stream>>>(x, y, fb0, fb1, fb2, fa1, fa2);
    (void)in_sizes; (void)n_in; (void)out_size; (void)d_ws; (void)ws_size;
}